// Round 9
// baseline (9392.398 us; speedup 1.0000x reference)
//
#include <hip/hip_runtime.h>
#include <hip/hip_bf16.h>

// TextRNN: embed -> 2-layer LSTM (B=64,T=256,H=1024) -> proj 32000, f32 out.
// R9 = R7 (split-K wave pairs, direct 64-slot poll, L3 h-ring) with ONE change:
// the 48 weight s16x8 per thread are PINNED INTO AGPRs via inline-asm "a"
// constraints (re-pinned every round). R5-R8 evidence: allocator caps at 128
// VGPR and re-streams ~96MB/round of weights through L2/L3 -> that, not sync
// hops, is the hypothesized 7.3us/round floor (explains R6/R7 neutrality).
// gfx950 MFMA reads B from AGPRs directly; unified RF has room (192a+~110v).

typedef __attribute__((ext_vector_type(8))) short s16x8;
typedef __attribute__((ext_vector_type(4))) float f32x4;
typedef unsigned long long u64;
typedef unsigned u32;

#define N_CLASS 32000
#define EMB 512
#define HID 1024
#define BATCH 64
#define SEQ 256
#define NG4 4096

// weight register quad, forced into AGPR class
struct wreg { u32 x, y, z, w; };
static __device__ __forceinline__ void pina(wreg& r) {
  asm volatile("" : "+a"(r.x), "+a"(r.y), "+a"(r.z), "+a"(r.w));
}
static __device__ __forceinline__ wreg topack(s16x8 v) {
  union { s16x8 v; wreg r; } t;
  t.v = v;
  return t.r;
}
static __device__ __forceinline__ s16x8 wval(wreg r) {
  union { wreg r; s16x8 v; } t;
  t.r = r;
  return t.v;
}

static __device__ __forceinline__ short f2bf(float x) {
  __hip_bfloat16 h = __float2bfloat16(x);
  return *reinterpret_cast<short*>(&h);
}
static __device__ __forceinline__ float bf2f(short x) {
  __hip_bfloat16 h = *reinterpret_cast<__hip_bfloat16*>(&x);
  return __bfloat162float(h);
}
static __device__ __forceinline__ float fsigm(float x) {
  return __builtin_amdgcn_rcpf(1.f + __expf(-x));
}
static __device__ __forceinline__ float ftanh(float x) {
  return 2.f * __builtin_amdgcn_rcpf(1.f + __expf(-2.f * x)) - 1.f;
}

// ---- weight conversion to swizzled bf16 B-layout: sw[((k>>3)*4096+n)*8+(k&7)]
__global__ void k_conv_w4(const float* __restrict__ Wg, const float* __restrict__ Wi,
                          const float* __restrict__ Wf, const float* __restrict__ Wo,
                          short* __restrict__ sw, int K) {
  int i = blockIdx.x * 256 + threadIdx.x;
  int k8 = i >> 10, j = i & 1023;
  if (k8 >= (K >> 3)) return;
  const float* W = blockIdx.z == 0 ? Wg : blockIdx.z == 1 ? Wi : blockIdx.z == 2 ? Wf : Wo;
  s16x8 v;
#pragma unroll
  for (int e = 0; e < 8; ++e) v[e] = f2bf(W[(size_t)(k8 * 8 + e) * 1024 + j]);
  *(s16x8*)(sw + ((size_t)k8 * NG4 + blockIdx.z * 1024 + j) * 8) = v;
}

__global__ void k_bcat(const float* __restrict__ b0, const float* __restrict__ b1,
                       const float* __restrict__ b2, const float* __restrict__ b3,
                       float* __restrict__ dst) {
  int i = blockIdx.x * 256 + threadIdx.x;  // 4096
  const float* s = (i >> 10) == 0 ? b0 : (i >> 10) == 1 ? b1 : (i >> 10) == 2 ? b2 : b3;
  dst[i] = s[i & 1023];
}

__global__ void k_f2bf(const float* __restrict__ src, short* __restrict__ dst, int n) {
  int i = blockIdx.x * 256 + threadIdx.x;
  if (i < n) dst[i] = f2bf(src[i]);
}

// ---- embedding gather --------------------------------------------------------
__global__ void k_embed(const int* __restrict__ X, const float* __restrict__ C,
                        short* __restrict__ xs) {
  int r = blockIdx.x;
  int t = r >> 6, b = r & 63;
  int idx = X[b * SEQ + t];
  const float* src = C + (size_t)idx * EMB;
  float2 v = *(const float2*)(src + threadIdx.x * 2);
  short* dst = xs + (size_t)r * EMB + threadIdx.x * 2;
  dst[0] = f2bf(v.x);
  dst[1] = f2bf(v.y);
}

// ---- G1 pre-GEMM: Gsw (bf16 packed u64) = xs@Wx1 + b1 ------------------------
__global__ __launch_bounds__(256) void k_gemx(const short* __restrict__ A,
                                              const short* __restrict__ Bsw,
                                              const float* __restrict__ bias,
                                              u64* __restrict__ Gsw) {
  __shared__ short lds[4096 * 8];  // 64KB B panel (K=512 x BN=64)
  int tid = threadIdx.x;
  int n0 = blockIdx.x * 64;
  for (int cid = tid; cid < 4096; cid += 256) {
    int k8 = cid >> 6, nl = cid & 63;
    *(s16x8*)(lds + (size_t)cid * 8) = *(const s16x8*)(Bsw + ((size_t)k8 * NG4 + n0 + nl) * 8);
  }
  __syncthreads();
  int lane = tid & 63, wid = tid >> 6;
  int l15 = lane & 15, l4 = lane >> 4;
  int ms = wid >> 1, ns = wid & 1;
  for (int m0 = blockIdx.y * 64; m0 < SEQ * BATCH; m0 += gridDim.y * 64) {
    f32x4 acc[2][2];
#pragma unroll
    for (int i = 0; i < 2; ++i)
#pragma unroll
      for (int j = 0; j < 2; ++j) acc[i][j] = (f32x4){0.f, 0.f, 0.f, 0.f};
    const short* a0p = A + (size_t)(m0 + ms * 32 + l15) * EMB + l4 * 8;
    const short* a1p = a0p + (size_t)16 * EMB;
#pragma unroll 4
    for (int kc = 0; kc < 16; ++kc) {
      s16x8 av0 = *(const s16x8*)(a0p + kc * 32);
      s16x8 av1 = *(const s16x8*)(a1p + kc * 32);
#pragma unroll
      for (int j = 0; j < 2; ++j) {
        s16x8 bv = *(const s16x8*)(lds + (size_t)((kc * 4 + l4) * 64 + ns * 32 + j * 16 + l15) * 8);
        acc[0][j] = __builtin_amdgcn_mfma_f32_16x16x32_bf16(av0, bv, acc[0][j], 0, 0, 0);
        acc[1][j] = __builtin_amdgcn_mfma_f32_16x16x32_bf16(av1, bv, acc[1][j], 0, 0, 0);
      }
    }
    int t = m0 >> 6;
#pragma unroll
    for (int i = 0; i < 2; ++i)
#pragma unroll
      for (int j = 0; j < 2; ++j) {
        int grp = ms * 2 + i;
        int colg = n0 + ns * 32 + j * 16 + l15;
        float bv = bias[colg];
        int q = colg >> 10, nslc = (colg >> 4) & 63;
        u64 pk = 0;
#pragma unroll
        for (int e = 0; e < 4; ++e)
          pk |= (u64)(unsigned short)f2bf(acc[i][j][e] + bv) << (16 * e);
        size_t slot = ((((size_t)t * 4 + grp) * 64 + nslc) * 4 + q) * 64 + l4 * 16 + l15;
        Gsw[slot] = pk;
      }
  }
}

// ---- persistent 2-layer recurrence, split-K wave pairs, AGPR weights ---------
__global__ __launch_bounds__(512, 2) void k_mega(
    const u64* __restrict__ G64, const short* __restrict__ Wh1sw,
    const short* __restrict__ Wx2sw, const short* __restrict__ Wh2sw,
    const float* __restrict__ bc2, u64* __restrict__ h1ex, u64* __restrict__ h2ex,
    const float* __restrict__ c0, const float* __restrict__ c0y,
    u64* __restrict__ hTy, unsigned* __restrict__ flags) {
  __shared__ short a_lds[2 * 16 * 1024];  // 64KB: A1 | A2, XOR-swizzled rows
  __shared__ f32x4 xch[8][64];            // 8KB partial-sum exchange
  const int tid = threadIdx.x;
  const int lane = tid & 63, W = tid >> 6;
  const int wv = W & 3, khalf = W >> 2;
  const int l15 = lane & 15, l4 = lane >> 4;
  // XCD-aware remap: group g lives on XCD pair {2g, 2g+1}
  const int xcd = (int)blockIdx.x & 7;
  const int group = xcd >> 1;
  const int nsl = ((((int)blockIdx.x >> 3) << 1) | (xcd & 1));
  const int col = (l15 >> 2) * 1024 + nsl * 16 + wv * 4 + (l15 & 3);

  // 48 x s16x8 = 192 regs of weights, pinned into AGPRs.
  wreg b1r[16], bxr[16], b2r[16];
#pragma unroll
  for (int j = 0; j < 16; ++j) {
    size_t o = ((size_t)((khalf * 16 + j) * 4 + l4) * NG4 + col) * 8;
    b1r[j] = topack(*(const s16x8*)(Wh1sw + o));
    bxr[j] = topack(*(const s16x8*)(Wx2sw + o));
    b2r[j] = topack(*(const s16x8*)(Wh2sw + o));
    pina(b1r[j]);
    pina(bxr[j]);
    pina(b2r[j]);
  }
  const float bias2 = bc2[col];
  float cv[4];  // c1 on waves 0-3, c2 on waves 4-7
#pragma unroll
  for (int e = 0; e < 4; ++e) {
    int gi = (group * 16 + l4 * 4 + e) * HID + nsl * 16 + wv * 4 + (l15 & 3);
    cv[e] = (W < 4 ? c0 : c0y)[gi];
  }
  unsigned* arr = flags;  // [4][64] slots, stride 32 u32 (128B)
  const int srow = tid >> 5, sc5 = tid & 31;
  const int exrow = (group * 16 + srow) * 256;
  const size_t gbase =
      (((size_t)group * 64 + nsl) * 4 + (l15 >> 2)) * 64 + l4 * 16 + wv * 4 + (l15 & 3);
  u64 gcur = (W < 4) ? G64[gbase] : 0;
  u64 gnext = 0;
  const int gsrc = l4 * 16 + (l15 & 3);
  const int psrc = ((l15 >> 2) << 4) + ((l15 & 3) << 2);
  const int swzm = (l15 & 7) << 4;
  const int abase = l15 * 2048 + khalf * 1024 + l4 * 16;

  for (int r = 0; r <= 256; ++r) {
    // prefetch G(r+1): issued BEFORE the spin so HBM latency hides in it
    if (W < 4 && r + 1 < 256) gnext = G64[gbase + (size_t)(r + 1) * 65536];
    if (r > 0) {
      if (tid < 64) {
        unsigned* p = arr + ((group << 6) + tid) * 32;
        while (__hip_atomic_load(p, __ATOMIC_RELAXED, __HIP_MEMORY_SCOPE_AGENT) <
               (unsigned)r) {
        }
      }
      __syncthreads();
      asm volatile("" ::: "memory");
    }
    {  // stage A1 = h1(r-1), A2 = h2(r-2) from ring slot (r+1)&1
      const int slot = (r + 1) & 1;
      const u64* s1 = h1ex + slot * 16384 + exrow;
      const u64* s2 = h2ex + slot * 16384 + exrow;
#pragma unroll
      for (int i = 0; i < 8; ++i) {
        int chunk = sc5 + (i << 5);
        u64 v1 = __hip_atomic_load(s1 + chunk, __ATOMIC_RELAXED, __HIP_MEMORY_SCOPE_AGENT);
        u64 v2 = __hip_atomic_load(s2 + chunk, __ATOMIC_RELAXED, __HIP_MEMORY_SCOPE_AGENT);
        int bo = (srow * 2048 + chunk * 8) ^ ((srow & 7) << 4);
        *(u64*)((char*)a_lds + bo) = v1;
        *(u64*)((char*)a_lds + 32768 + bo) = v2;
      }
    }
    __syncthreads();
    // re-pin weights each round: blocks any remat/copy-out across iterations
#pragma unroll
    for (int j = 0; j < 16; ++j) {
      pina(b1r[j]);
      pina(bxr[j]);
      pina(b2r[j]);
    }

    // ---- MFMA: 3 chains (L1, L2-x, L2-h), 16 deep each (this wave's K half)
    f32x4 p1, p2a, p2b;
    if (W < 4) {
#pragma unroll
      for (int e = 0; e < 4; ++e)
        p1[e] = __uint_as_float((unsigned)((gcur >> (16 * e)) & 0xffffu) << 16);
      p2a = (f32x4){0.f, 0.f, 0.f, 0.f};
    } else {
      p1 = (f32x4){0.f, 0.f, 0.f, 0.f};
      p2a = (f32x4){bias2, bias2, bias2, bias2};
    }
    p2b = (f32x4){0.f, 0.f, 0.f, 0.f};
#pragma unroll
    for (int j = 0; j < 16; ++j) {
      int o = (abase + j * 64) ^ swzm;
      s16x8 a1 = *(const s16x8*)((const char*)a_lds + o);
      s16x8 a2 = *(const s16x8*)((const char*)a_lds + 32768 + o);
      p1 = __builtin_amdgcn_mfma_f32_16x16x32_bf16(a1, wval(b1r[j]), p1, 0, 0, 0);
      p2a = __builtin_amdgcn_mfma_f32_16x16x32_bf16(a1, wval(bxr[j]), p2a, 0, 0, 0);
      p2b = __builtin_amdgcn_mfma_f32_16x16x32_bf16(a2, wval(b2r[j]), p2b, 0, 0, 0);
    }
    f32x4 p2 = p2a + p2b;
    // ---- cross-wave-pair partial exchange
    if (W < 4) {
      if (r >= 1) xch[W][lane] = p2;
    } else {
      if (r < 256) xch[W][lane] = p1;
    }
    __syncthreads();

    if (W < 4) {
      if (r < 256) {  // layer-1 activation, h1(r)
        f32x4 po = xch[W + 4][lane];
        f32x4 acc = p1 + po;
        float hh0, hh1, hh2, hh3;
#pragma unroll
        for (int e = 0; e < 4; ++e) {
          float xg = __shfl(acc[e], gsrc + 0);
          float xi = __shfl(acc[e], gsrc + 4);
          float xf = __shfl(acc[e], gsrc + 8);
          float xo = __shfl(acc[e], gsrc + 12);
          float cn = cv[e] * fsigm(xf) + ftanh(xg) * fsigm(xi);
          cv[e] = cn;
          float hv = ftanh(cn) * fsigm(xo);
          if (e == 0) hh0 = hv;
          else if (e == 1) hh1 = hv;
          else if (e == 2) hh2 = hv;
          else hh3 = hv;
        }
        int rr = l15 >> 2;
        float hexp = rr == 0 ? hh0 : rr == 1 ? hh1 : rr == 2 ? hh2 : hh3;
        float p0 = __shfl(hexp, psrc + 0);
        float p1s = __shfl(hexp, psrc + 1);
        float p2s = __shfl(hexp, psrc + 2);
        float p3s = __shfl(hexp, psrc + 3);
        if (lane < 16) {
          u64 pk = (u64)(unsigned short)f2bf(p0) | ((u64)(unsigned short)f2bf(p1s) << 16) |
                   ((u64)(unsigned short)f2bf(p2s) << 32) |
                   ((u64)(unsigned short)f2bf(p3s) << 48);
          __hip_atomic_store(
              h1ex + (r & 1) * 16384 + (group * 16 + lane) * 256 + nsl * 4 + wv, pk,
              __ATOMIC_RELAXED, __HIP_MEMORY_SCOPE_AGENT);
        }
      }
    } else {
      if (r >= 1) {  // layer-2 activation, h2(r-1)
        f32x4 po = xch[W - 4][lane];
        f32x4 acc = p2 + po;
        float hh0, hh1, hh2, hh3;
#pragma unroll
        for (int e = 0; e < 4; ++e) {
          float xg = __shfl(acc[e], gsrc + 0);
          float xi = __shfl(acc[e], gsrc + 4);
          float xf = __shfl(acc[e], gsrc + 8);
          float xo = __shfl(acc[e], gsrc + 12);
          float cn = cv[e] * fsigm(xf) + ftanh(xg) * fsigm(xi);
          cv[e] = cn;
          float hv = ftanh(cn) * fsigm(xo);
          if (e == 0) hh0 = hv;
          else if (e == 1) hh1 = hv;
          else if (e == 2) hh2 = hv;
          else hh3 = hv;
        }
        int rr = l15 >> 2;
        float hexp = rr == 0 ? hh0 : rr == 1 ? hh1 : rr == 2 ? hh2 : hh3;
        float p0 = __shfl(hexp, psrc + 0);
        float p1s = __shfl(hexp, psrc + 1);
        float p2s = __shfl(hexp, psrc + 2);
        float p3s = __shfl(hexp, psrc + 3);
        if (lane < 16) {
          u64 pk = (u64)(unsigned short)f2bf(p0) | ((u64)(unsigned short)f2bf(p1s) << 16) |
                   ((u64)(unsigned short)f2bf(p2s) << 32) |
                   ((u64)(unsigned short)f2bf(p3s) << 48);
          int idx = (group * 16 + lane) * 256 + nsl * 4 + wv;
          if (r < 256)
            __hip_atomic_store(h2ex + (r & 1) * 16384 + idx, pk, __ATOMIC_RELAXED,
                               __HIP_MEMORY_SCOPE_AGENT);
          else
            hTy[idx] = pk;  // h2(255) = hT_y
        }
      }
    }

    if (r < 256) {
      asm volatile("s_waitcnt vmcnt(0)" ::: "memory");
      __syncthreads();
      if (tid == 0)
        __hip_atomic_store(arr + ((group << 6) + nsl) * 32, (unsigned)(r + 1),
                           __ATOMIC_RELAXED, __HIP_MEMORY_SCOPE_AGENT);
    }
    gcur = gnext;
  }
}

// ---- final projection, split-K=2 --------------------------------------------
__global__ __launch_bounds__(256) void k_final(const short* __restrict__ hT,
                                               const float* __restrict__ W3,
                                               float* __restrict__ partial) {
  __shared__ float hst[64][64];
  int tid = threadIdx.x;
  int n = blockIdx.x * 256 + tid;
  int kbase = blockIdx.y * 512;
  float acc[64];
#pragma unroll
  for (int i = 0; i < 64; ++i) acc[i] = 0.f;
  int bb = tid >> 2, part = tid & 3;
  for (int kc = 0; kc < 512; kc += 64) {
    __syncthreads();
    s16x8 v0 = *(const s16x8*)(hT + bb * HID + kbase + kc + part * 16);
    s16x8 v1 = *(const s16x8*)(hT + bb * HID + kbase + kc + part * 16 + 8);
#pragma unroll
    for (int e = 0; e < 8; ++e) {
      hst[part * 16 + e][bb] = bf2f(v0[e]);
      hst[part * 16 + 8 + e][bb] = bf2f(v1[e]);
    }
    __syncthreads();
    for (int k = 0; k < 64; ++k) {
      float wv = W3[(size_t)(kbase + kc + k) * N_CLASS + n];
      const float4* hp = (const float4*)&hst[k][0];
#pragma unroll
      for (int b4 = 0; b4 < 16; ++b4) {
        float4 h4 = hp[b4];
        acc[b4 * 4 + 0] += h4.x * wv;
        acc[b4 * 4 + 1] += h4.y * wv;
        acc[b4 * 4 + 2] += h4.z * wv;
        acc[b4 * 4 + 3] += h4.w * wv;
      }
    }
  }
#pragma unroll
  for (int b = 0; b < 64; ++b)
    partial[((size_t)blockIdx.y * 64 + b) * N_CLASS + n] = acc[b];
}

__global__ void k_fincomb(const float* __restrict__ partial, const float* __restrict__ b2,
                          float* __restrict__ out) {
  int n = blockIdx.x * 256 + threadIdx.x;
  int b = blockIdx.y;
  out[(size_t)b * N_CLASS + n] =
      partial[(size_t)b * N_CLASS + n] + partial[((size_t)64 + b) * N_CLASS + n] + b2[n];
}

extern "C" void kernel_launch(void* const* d_in, const int* in_sizes, int n_in, void* d_out,
                              int out_size, void* d_ws, size_t ws_size, hipStream_t stream) {
  (void)in_sizes; (void)n_in; (void)out_size; (void)ws_size;
  const int* X = (const int*)d_in[0];
  const float* C = (const float*)d_in[1];
  const float* W1 = (const float*)d_in[2];
  const float* W_xi = (const float*)d_in[3];
  const float* W_xf = (const float*)d_in[4];
  const float* W_xo = (const float*)d_in[5];
  const float* W2 = (const float*)d_in[6];
  const float* W_hi = (const float*)d_in[7];
  const float* W_hf = (const float*)d_in[8];
  const float* W_ho = (const float*)d_in[9];
  const float* b1 = (const float*)d_in[10];
  const float* b_i = (const float*)d_in[11];
  const float* b_f = (const float*)d_in[12];
  const float* b_o = (const float*)d_in[13];
  const float* W1_y = (const float*)d_in[14];
  const float* W_xi_y = (const float*)d_in[15];
  const float* W_xf_y = (const float*)d_in[16];
  const float* W_xo_y = (const float*)d_in[17];
  const float* W2_y = (const float*)d_in[18];
  const float* W_hi_y = (const float*)d_in[19];
  const float* W_hf_y = (const float*)d_in[20];
  const float* W_ho_y = (const float*)d_in[21];
  const float* b1_y = (const float*)d_in[22];
  const float* b_i_y = (const float*)d_in[23];
  const float* b_f_y = (const float*)d_in[24];
  const float* b_o_y = (const float*)d_in[25];
  const float* W3 = (const float*)d_in[26];
  const float* b2 = (const float*)d_in[27];
  const float* h0 = (const float*)d_in[28];
  const float* c0 = (const float*)d_in[29];
  const float* h0_y = (const float*)d_in[30];
  const float* c0_y = (const float*)d_in[31];

  char* w = (char*)d_ws;
  size_t off = 0;
  auto take = [&](size_t bytes) {
    char* p = w + off;
    off += (bytes + 255) & ~(size_t)255;
    return p;
  };
  short* wx1 = (short*)take(64UL * NG4 * 8 * 2);
  short* wh1 = (short*)take(128UL * NG4 * 8 * 2);
  short* wx2 = (short*)take(128UL * NG4 * 8 * 2);
  short* wh2 = (short*)take(128UL * NG4 * 8 * 2);
  short* xs = (short*)take((size_t)SEQ * BATCH * EMB * 2);
  u64* G1sw = (u64*)take((size_t)SEQ * 65536 * 8);  // 134MB; partials alias later
  float* bc1 = (float*)take(NG4 * 4);
  float* bc2 = (float*)take(NG4 * 4);
  u64* h1ex = (u64*)take(2UL * 16384 * 8);
  u64* h2ex = (u64*)take(2UL * 16384 * 8);
  u64* hTy = (u64*)take(16384UL * 8);
  unsigned* flags = (unsigned*)take(65536);

  hipMemsetAsync(flags, 0, 65536, stream);
  k_bcat<<<16, 256, 0, stream>>>(b1, b_i, b_f, b_o, bc1);
  k_bcat<<<16, 256, 0, stream>>>(b1_y, b_i_y, b_f_y, b_o_y, bc2);
  k_f2bf<<<256, 256, 0, stream>>>(h0, (short*)h1ex + 65536, BATCH * HID);
  k_f2bf<<<256, 256, 0, stream>>>(h0_y, (short*)h2ex, BATCH * HID);
  k_conv_w4<<<dim3(256, 1, 4), 256, 0, stream>>>(W1, W_xi, W_xf, W_xo, wx1, 512);
  k_conv_w4<<<dim3(512, 1, 4), 256, 0, stream>>>(W2, W_hi, W_hf, W_ho, wh1, 1024);
  k_conv_w4<<<dim3(512, 1, 4), 256, 0, stream>>>(W1_y, W_xi_y, W_xf_y, W_xo_y, wx2, 1024);
  k_conv_w4<<<dim3(512, 1, 4), 256, 0, stream>>>(W2_y, W_hi_y, W_hf_y, W_ho_y, wh2, 1024);
  k_embed<<<SEQ * BATCH, 256, 0, stream>>>(X, C, xs);
  k_gemx<<<dim3(64, 16), 256, 0, stream>>>(xs, wx1, bc1, G1sw);
  k_mega<<<256, 512, 0, stream>>>(G1sw, wh1, wx2, wh2, bc2, h1ex, h2ex, c0, c0_y, hTy,
                                  flags);
  float* partial = (float*)G1sw;
  k_final<<<dim3(125, 2), 256, 0, stream>>>((const short*)hTy, W3, partial);
  k_fincomb<<<dim3(125, 64), 256, 0, stream>>>(partial, b2, (float*)d_out);
}

// Round 10
// 2362.888 us; speedup vs baseline: 3.9750x; 3.9750x over previous
//
#include <hip/hip_runtime.h>
#include <hip/hip_bf16.h>

// TextRNN: embed -> 2-layer LSTM (B=64,T=256,H=1024) -> proj 32000, f32 out.
// R10 = R7 with ONE change: block->(group,nsl) mapping colocates all 4 group-
// copies of each nsl (identical 384KB weight slice) on ONE XCD, and puts only
// 8 distinct nsl slices per XCD: 8 x 384KB = 3.07MB < 4MB L2. The per-round
// 96MB weight re-stream (allocator caps at 128 VGPR, re-reads weights every
// round) then runs at L2 speed instead of saturating die-level L3 at 13TB/s
// -- which the R4-R9 evidence identifies as the 7.4us/round floor.

typedef __attribute__((ext_vector_type(8))) short s16x8;
typedef __attribute__((ext_vector_type(4))) float f32x4;
typedef unsigned long long u64;

#define N_CLASS 32000
#define EMB 512
#define HID 1024
#define BATCH 64
#define SEQ 256
#define NG4 4096

#define PIN(v) asm volatile("" : "+v"(v))

static __device__ __forceinline__ short f2bf(float x) {
  __hip_bfloat16 h = __float2bfloat16(x);
  return *reinterpret_cast<short*>(&h);
}
static __device__ __forceinline__ float bf2f(short x) {
  __hip_bfloat16 h = *reinterpret_cast<__hip_bfloat16*>(&x);
  return __bfloat162float(h);
}
static __device__ __forceinline__ float fsigm(float x) {
  return __builtin_amdgcn_rcpf(1.f + __expf(-x));
}
static __device__ __forceinline__ float ftanh(float x) {
  return 2.f * __builtin_amdgcn_rcpf(1.f + __expf(-2.f * x)) - 1.f;
}

// ---- weight conversion to swizzled bf16 B-layout: sw[((k>>3)*4096+n)*8+(k&7)]
__global__ void k_conv_w4(const float* __restrict__ Wg, const float* __restrict__ Wi,
                          const float* __restrict__ Wf, const float* __restrict__ Wo,
                          short* __restrict__ sw, int K) {
  int i = blockIdx.x * 256 + threadIdx.x;
  int k8 = i >> 10, j = i & 1023;
  if (k8 >= (K >> 3)) return;
  const float* W = blockIdx.z == 0 ? Wg : blockIdx.z == 1 ? Wi : blockIdx.z == 2 ? Wf : Wo;
  s16x8 v;
#pragma unroll
  for (int e = 0; e < 8; ++e) v[e] = f2bf(W[(size_t)(k8 * 8 + e) * 1024 + j]);
  *(s16x8*)(sw + ((size_t)k8 * NG4 + blockIdx.z * 1024 + j) * 8) = v;
}

__global__ void k_bcat(const float* __restrict__ b0, const float* __restrict__ b1,
                       const float* __restrict__ b2, const float* __restrict__ b3,
                       float* __restrict__ dst) {
  int i = blockIdx.x * 256 + threadIdx.x;  // 4096
  const float* s = (i >> 10) == 0 ? b0 : (i >> 10) == 1 ? b1 : (i >> 10) == 2 ? b2 : b3;
  dst[i] = s[i & 1023];
}

__global__ void k_f2bf(const float* __restrict__ src, short* __restrict__ dst, int n) {
  int i = blockIdx.x * 256 + threadIdx.x;
  if (i < n) dst[i] = f2bf(src[i]);
}

// ---- embedding gather --------------------------------------------------------
__global__ void k_embed(const int* __restrict__ X, const float* __restrict__ C,
                        short* __restrict__ xs) {
  int r = blockIdx.x;
  int t = r >> 6, b = r & 63;
  int idx = X[b * SEQ + t];
  const float* src = C + (size_t)idx * EMB;
  float2 v = *(const float2*)(src + threadIdx.x * 2);
  short* dst = xs + (size_t)r * EMB + threadIdx.x * 2;
  dst[0] = f2bf(v.x);
  dst[1] = f2bf(v.y);
}

// ---- G1 pre-GEMM: Gsw (bf16 packed u64) = xs@Wx1 + b1 ------------------------
__global__ __launch_bounds__(256) void k_gemx(const short* __restrict__ A,
                                              const short* __restrict__ Bsw,
                                              const float* __restrict__ bias,
                                              u64* __restrict__ Gsw) {
  __shared__ short lds[4096 * 8];  // 64KB B panel (K=512 x BN=64)
  int tid = threadIdx.x;
  int n0 = blockIdx.x * 64;
  for (int cid = tid; cid < 4096; cid += 256) {
    int k8 = cid >> 6, nl = cid & 63;
    *(s16x8*)(lds + (size_t)cid * 8) = *(const s16x8*)(Bsw + ((size_t)k8 * NG4 + n0 + nl) * 8);
  }
  __syncthreads();
  int lane = tid & 63, wid = tid >> 6;
  int l15 = lane & 15, l4 = lane >> 4;
  int ms = wid >> 1, ns = wid & 1;
  for (int m0 = blockIdx.y * 64; m0 < SEQ * BATCH; m0 += gridDim.y * 64) {
    f32x4 acc[2][2];
#pragma unroll
    for (int i = 0; i < 2; ++i)
#pragma unroll
      for (int j = 0; j < 2; ++j) acc[i][j] = (f32x4){0.f, 0.f, 0.f, 0.f};
    const short* a0p = A + (size_t)(m0 + ms * 32 + l15) * EMB + l4 * 8;
    const short* a1p = a0p + (size_t)16 * EMB;
#pragma unroll 4
    for (int kc = 0; kc < 16; ++kc) {
      s16x8 av0 = *(const s16x8*)(a0p + kc * 32);
      s16x8 av1 = *(const s16x8*)(a1p + kc * 32);
#pragma unroll
      for (int j = 0; j < 2; ++j) {
        s16x8 bv = *(const s16x8*)(lds + (size_t)((kc * 4 + l4) * 64 + ns * 32 + j * 16 + l15) * 8);
        acc[0][j] = __builtin_amdgcn_mfma_f32_16x16x32_bf16(av0, bv, acc[0][j], 0, 0, 0);
        acc[1][j] = __builtin_amdgcn_mfma_f32_16x16x32_bf16(av1, bv, acc[1][j], 0, 0, 0);
      }
    }
    int t = m0 >> 6;
#pragma unroll
    for (int i = 0; i < 2; ++i)
#pragma unroll
      for (int j = 0; j < 2; ++j) {
        int grp = ms * 2 + i;
        int colg = n0 + ns * 32 + j * 16 + l15;
        float bv = bias[colg];
        int q = colg >> 10, nslc = (colg >> 4) & 63;
        u64 pk = 0;
#pragma unroll
        for (int e = 0; e < 4; ++e)
          pk |= (u64)(unsigned short)f2bf(acc[i][j][e] + bv) << (16 * e);
        size_t slot = ((((size_t)t * 4 + grp) * 64 + nslc) * 4 + q) * 64 + l4 * 16 + l15;
        Gsw[slot] = pk;
      }
  }
}

// ---- persistent 2-layer recurrence, split-K wave pairs -----------------------
__global__ __launch_bounds__(512, 2) void k_mega(
    const u64* __restrict__ G64, const short* __restrict__ Wh1sw,
    const short* __restrict__ Wx2sw, const short* __restrict__ Wh2sw,
    const float* __restrict__ bc2, u64* __restrict__ h1ex, u64* __restrict__ h2ex,
    const float* __restrict__ c0, const float* __restrict__ c0y,
    u64* __restrict__ hTy, unsigned* __restrict__ flags) {
  __shared__ short a_lds[2 * 16 * 1024];  // 64KB: A1 | A2, XOR-swizzled rows
  __shared__ f32x4 xch[8][64];            // 8KB partial-sum exchange
  const int tid = threadIdx.x;
  const int lane = tid & 63, W = tid >> 6;
  const int wv = W & 3, khalf = W >> 2;
  const int l15 = lane & 15, l4 = lane >> 4;
  // nsl-colocating XCD remap: xcd = nsl&7, so all 4 group-copies of a weight
  // slice land on one XCD and only 8 distinct slices (3.07MB) live per L2.
  const int xcd = (int)blockIdx.x & 7;
  const int idx = (int)blockIdx.x >> 3;        // 0..31
  const int group = idx & 3;
  const int nsl = ((idx >> 2) << 3) | xcd;     // 8*(idx>>2) + xcd
  const int col = (l15 >> 2) * 1024 + nsl * 16 + wv * 4 + (l15 & 3);

  // 48 x s16x8 = 192 VGPR of weights; static indices + pin at load.
  s16x8 b1r[16], bxr[16], b2r[16];
#pragma unroll
  for (int j = 0; j < 16; ++j) {
    size_t o = ((size_t)((khalf * 16 + j) * 4 + l4) * NG4 + col) * 8;
    b1r[j] = *(const s16x8*)(Wh1sw + o);
    PIN(b1r[j]);
  }
#pragma unroll
  for (int j = 0; j < 16; ++j) {
    size_t o = ((size_t)((khalf * 16 + j) * 4 + l4) * NG4 + col) * 8;
    bxr[j] = *(const s16x8*)(Wx2sw + o);
    PIN(bxr[j]);
  }
#pragma unroll
  for (int j = 0; j < 16; ++j) {
    size_t o = ((size_t)((khalf * 16 + j) * 4 + l4) * NG4 + col) * 8;
    b2r[j] = *(const s16x8*)(Wh2sw + o);
    PIN(b2r[j]);
  }
  const float bias2 = bc2[col];
  float cv[4];  // c1 on waves 0-3, c2 on waves 4-7
#pragma unroll
  for (int e = 0; e < 4; ++e) {
    int gi = (group * 16 + l4 * 4 + e) * HID + nsl * 16 + wv * 4 + (l15 & 3);
    cv[e] = (W < 4 ? c0 : c0y)[gi];
  }
  unsigned* arr = flags;  // [4][64] slots, stride 32 u32 (128B)
  const int srow = tid >> 5, sc5 = tid & 31;
  const int exrow = (group * 16 + srow) * 256;
  const size_t gbase =
      (((size_t)group * 64 + nsl) * 4 + (l15 >> 2)) * 64 + l4 * 16 + wv * 4 + (l15 & 3);
  u64 gcur = (W < 4) ? G64[gbase] : 0;
  u64 gnext = 0;
  const int gsrc = l4 * 16 + (l15 & 3);
  const int psrc = ((l15 >> 2) << 4) + ((l15 & 3) << 2);
  const int swzm = (l15 & 7) << 4;
  const int abase = l15 * 2048 + khalf * 1024 + l4 * 16;

  for (int r = 0; r <= 256; ++r) {
    // prefetch G(r+1): issued BEFORE the spin so HBM latency hides in it
    if (W < 4 && r + 1 < 256) gnext = G64[gbase + (size_t)(r + 1) * 65536];
    if (r > 0) {
      if (tid < 64) {
        unsigned* p = arr + ((group << 6) + tid) * 32;
        while (__hip_atomic_load(p, __ATOMIC_RELAXED, __HIP_MEMORY_SCOPE_AGENT) <
               (unsigned)r)
          __builtin_amdgcn_s_sleep(1);
      }
      __syncthreads();
      asm volatile("" ::: "memory");
    }
    {  // stage A1 = h1(r-1), A2 = h2(r-2) from ring slot (r+1)&1
      const int slot = (r + 1) & 1;
      const u64* s1 = h1ex + slot * 16384 + exrow;
      const u64* s2 = h2ex + slot * 16384 + exrow;
#pragma unroll
      for (int i = 0; i < 8; ++i) {
        int chunk = sc5 + (i << 5);
        u64 v1 = __hip_atomic_load(s1 + chunk, __ATOMIC_RELAXED, __HIP_MEMORY_SCOPE_AGENT);
        u64 v2 = __hip_atomic_load(s2 + chunk, __ATOMIC_RELAXED, __HIP_MEMORY_SCOPE_AGENT);
        int bo = (srow * 2048 + chunk * 8) ^ ((srow & 7) << 4);
        *(u64*)((char*)a_lds + bo) = v1;
        *(u64*)((char*)a_lds + 32768 + bo) = v2;
      }
    }
    __syncthreads();

    // ---- MFMA: 3 chains (L1, L2-x, L2-h), 16 deep each (this wave's K half)
    f32x4 p1, p2a, p2b;
    if (W < 4) {
#pragma unroll
      for (int e = 0; e < 4; ++e)
        p1[e] = __uint_as_float((unsigned)((gcur >> (16 * e)) & 0xffffu) << 16);
      p2a = (f32x4){0.f, 0.f, 0.f, 0.f};
    } else {
      p1 = (f32x4){0.f, 0.f, 0.f, 0.f};
      p2a = (f32x4){bias2, bias2, bias2, bias2};
    }
    p2b = (f32x4){0.f, 0.f, 0.f, 0.f};
#pragma unroll
    for (int j = 0; j < 16; ++j) {
      int o = (abase + j * 64) ^ swzm;
      s16x8 a1 = *(const s16x8*)((const char*)a_lds + o);
      s16x8 a2 = *(const s16x8*)((const char*)a_lds + 32768 + o);
      p1 = __builtin_amdgcn_mfma_f32_16x16x32_bf16(a1, b1r[j], p1, 0, 0, 0);
      p2a = __builtin_amdgcn_mfma_f32_16x16x32_bf16(a1, bxr[j], p2a, 0, 0, 0);
      p2b = __builtin_amdgcn_mfma_f32_16x16x32_bf16(a2, b2r[j], p2b, 0, 0, 0);
    }
    f32x4 p2 = p2a + p2b;
    // ---- cross-wave-pair partial exchange
    if (W < 4) {
      if (r >= 1) xch[W][lane] = p2;
    } else {
      if (r < 256) xch[W][lane] = p1;
    }
    __syncthreads();

    if (W < 4) {
      if (r < 256) {  // layer-1 activation, h1(r)
        f32x4 po = xch[W + 4][lane];
        f32x4 acc = p1 + po;
        float hh0, hh1, hh2, hh3;
#pragma unroll
        for (int e = 0; e < 4; ++e) {
          float xg = __shfl(acc[e], gsrc + 0);
          float xi = __shfl(acc[e], gsrc + 4);
          float xf = __shfl(acc[e], gsrc + 8);
          float xo = __shfl(acc[e], gsrc + 12);
          float cn = cv[e] * fsigm(xf) + ftanh(xg) * fsigm(xi);
          cv[e] = cn;
          float hv = ftanh(cn) * fsigm(xo);
          if (e == 0) hh0 = hv;
          else if (e == 1) hh1 = hv;
          else if (e == 2) hh2 = hv;
          else hh3 = hv;
        }
        int rr = l15 >> 2;
        float hexp = rr == 0 ? hh0 : rr == 1 ? hh1 : rr == 2 ? hh2 : hh3;
        float p0 = __shfl(hexp, psrc + 0);
        float p1s = __shfl(hexp, psrc + 1);
        float p2s = __shfl(hexp, psrc + 2);
        float p3s = __shfl(hexp, psrc + 3);
        if (lane < 16) {
          u64 pk = (u64)(unsigned short)f2bf(p0) | ((u64)(unsigned short)f2bf(p1s) << 16) |
                   ((u64)(unsigned short)f2bf(p2s) << 32) |
                   ((u64)(unsigned short)f2bf(p3s) << 48);
          __hip_atomic_store(
              h1ex + (r & 1) * 16384 + (group * 16 + lane) * 256 + nsl * 4 + wv, pk,
              __ATOMIC_RELAXED, __HIP_MEMORY_SCOPE_AGENT);
        }
      }
    } else {
      if (r >= 1) {  // layer-2 activation, h2(r-1)
        f32x4 po = xch[W - 4][lane];
        f32x4 acc = p2 + po;
        float hh0, hh1, hh2, hh3;
#pragma unroll
        for (int e = 0; e < 4; ++e) {
          float xg = __shfl(acc[e], gsrc + 0);
          float xi = __shfl(acc[e], gsrc + 4);
          float xf = __shfl(acc[e], gsrc + 8);
          float xo = __shfl(acc[e], gsrc + 12);
          float cn = cv[e] * fsigm(xf) + ftanh(xg) * fsigm(xi);
          cv[e] = cn;
          float hv = ftanh(cn) * fsigm(xo);
          if (e == 0) hh0 = hv;
          else if (e == 1) hh1 = hv;
          else if (e == 2) hh2 = hv;
          else hh3 = hv;
        }
        int rr = l15 >> 2;
        float hexp = rr == 0 ? hh0 : rr == 1 ? hh1 : rr == 2 ? hh2 : hh3;
        float p0 = __shfl(hexp, psrc + 0);
        float p1s = __shfl(hexp, psrc + 1);
        float p2s = __shfl(hexp, psrc + 2);
        float p3s = __shfl(hexp, psrc + 3);
        if (lane < 16) {
          u64 pk = (u64)(unsigned short)f2bf(p0) | ((u64)(unsigned short)f2bf(p1s) << 16) |
                   ((u64)(unsigned short)f2bf(p2s) << 32) |
                   ((u64)(unsigned short)f2bf(p3s) << 48);
          int idx2 = (group * 16 + lane) * 256 + nsl * 4 + wv;
          if (r < 256)
            __hip_atomic_store(h2ex + (r & 1) * 16384 + idx2, pk, __ATOMIC_RELAXED,
                               __HIP_MEMORY_SCOPE_AGENT);
          else
            hTy[idx2] = pk;  // h2(255) = hT_y
        }
      }
    }

    if (r < 256) {
      asm volatile("s_waitcnt vmcnt(0)" ::: "memory");
      __syncthreads();
      if (tid == 0)
        __hip_atomic_store(arr + ((group << 6) + nsl) * 32, (unsigned)(r + 1),
                           __ATOMIC_RELAXED, __HIP_MEMORY_SCOPE_AGENT);
    }
    gcur = gnext;
  }
}

// ---- final projection, split-K=2 --------------------------------------------
__global__ __launch_bounds__(256) void k_final(const short* __restrict__ hT,
                                               const float* __restrict__ W3,
                                               float* __restrict__ partial) {
  __shared__ float hst[64][64];
  int tid = threadIdx.x;
  int n = blockIdx.x * 256 + tid;
  int kbase = blockIdx.y * 512;
  float acc[64];
#pragma unroll
  for (int i = 0; i < 64; ++i) acc[i] = 0.f;
  int bb = tid >> 2, part = tid & 3;
  for (int kc = 0; kc < 512; kc += 64) {
    __syncthreads();
    s16x8 v0 = *(const s16x8*)(hT + bb * HID + kbase + kc + part * 16);
    s16x8 v1 = *(const s16x8*)(hT + bb * HID + kbase + kc + part * 16 + 8);
#pragma unroll
    for (int e = 0; e < 8; ++e) {
      hst[part * 16 + e][bb] = bf2f(v0[e]);
      hst[part * 16 + 8 + e][bb] = bf2f(v1[e]);
    }
    __syncthreads();
    for (int k = 0; k < 64; ++k) {
      float wv = W3[(size_t)(kbase + kc + k) * N_CLASS + n];
      const float4* hp = (const float4*)&hst[k][0];
#pragma unroll
      for (int b4 = 0; b4 < 16; ++b4) {
        float4 h4 = hp[b4];
        acc[b4 * 4 + 0] += h4.x * wv;
        acc[b4 * 4 + 1] += h4.y * wv;
        acc[b4 * 4 + 2] += h4.z * wv;
        acc[b4 * 4 + 3] += h4.w * wv;
      }
    }
  }
#pragma unroll
  for (int b = 0; b < 64; ++b)
    partial[((size_t)blockIdx.y * 64 + b) * N_CLASS + n] = acc[b];
}

__global__ void k_fincomb(const float* __restrict__ partial, const float* __restrict__ b2,
                          float* __restrict__ out) {
  int n = blockIdx.x * 256 + threadIdx.x;
  int b = blockIdx.y;
  out[(size_t)b * N_CLASS + n] =
      partial[(size_t)b * N_CLASS + n] + partial[((size_t)64 + b) * N_CLASS + n] + b2[n];
}

extern "C" void kernel_launch(void* const* d_in, const int* in_sizes, int n_in, void* d_out,
                              int out_size, void* d_ws, size_t ws_size, hipStream_t stream) {
  (void)in_sizes; (void)n_in; (void)out_size; (void)ws_size;
  const int* X = (const int*)d_in[0];
  const float* C = (const float*)d_in[1];
  const float* W1 = (const float*)d_in[2];
  const float* W_xi = (const float*)d_in[3];
  const float* W_xf = (const float*)d_in[4];
  const float* W_xo = (const float*)d_in[5];
  const float* W2 = (const float*)d_in[6];
  const float* W_hi = (const float*)d_in[7];
  const float* W_hf = (const float*)d_in[8];
  const float* W_ho = (const float*)d_in[9];
  const float* b1 = (const float*)d_in[10];
  const float* b_i = (const float*)d_in[11];
  const float* b_f = (const float*)d_in[12];
  const float* b_o = (const float*)d_in[13];
  const float* W1_y = (const float*)d_in[14];
  const float* W_xi_y = (const float*)d_in[15];
  const float* W_xf_y = (const float*)d_in[16];
  const float* W_xo_y = (const float*)d_in[17];
  const float* W2_y = (const float*)d_in[18];
  const float* W_hi_y = (const float*)d_in[19];
  const float* W_hf_y = (const float*)d_in[20];
  const float* W_ho_y = (const float*)d_in[21];
  const float* b1_y = (const float*)d_in[22];
  const float* b_i_y = (const float*)d_in[23];
  const float* b_f_y = (const float*)d_in[24];
  const float* b_o_y = (const float*)d_in[25];
  const float* W3 = (const float*)d_in[26];
  const float* b2 = (const float*)d_in[27];
  const float* h0 = (const float*)d_in[28];
  const float* c0 = (const float*)d_in[29];
  const float* h0_y = (const float*)d_in[30];
  const float* c0_y = (const float*)d_in[31];

  char* w = (char*)d_ws;
  size_t off = 0;
  auto take = [&](size_t bytes) {
    char* p = w + off;
    off += (bytes + 255) & ~(size_t)255;
    return p;
  };
  short* wx1 = (short*)take(64UL * NG4 * 8 * 2);
  short* wh1 = (short*)take(128UL * NG4 * 8 * 2);
  short* wx2 = (short*)take(128UL * NG4 * 8 * 2);
  short* wh2 = (short*)take(128UL * NG4 * 8 * 2);
  short* xs = (short*)take((size_t)SEQ * BATCH * EMB * 2);
  u64* G1sw = (u64*)take((size_t)SEQ * 65536 * 8);  // 134MB; partials alias later
  float* bc1 = (float*)take(NG4 * 4);
  float* bc2 = (float*)take(NG4 * 4);
  u64* h1ex = (u64*)take(2UL * 16384 * 8);
  u64* h2ex = (u64*)take(2UL * 16384 * 8);
  u64* hTy = (u64*)take(16384UL * 8);
  unsigned* flags = (unsigned*)take(65536);

  hipMemsetAsync(flags, 0, 65536, stream);
  k_bcat<<<16, 256, 0, stream>>>(b1, b_i, b_f, b_o, bc1);
  k_bcat<<<16, 256, 0, stream>>>(b1_y, b_i_y, b_f_y, b_o_y, bc2);
  k_f2bf<<<256, 256, 0, stream>>>(h0, (short*)h1ex + 65536, BATCH * HID);
  k_f2bf<<<256, 256, 0, stream>>>(h0_y, (short*)h2ex, BATCH * HID);
  k_conv_w4<<<dim3(256, 1, 4), 256, 0, stream>>>(W1, W_xi, W_xf, W_xo, wx1, 512);
  k_conv_w4<<<dim3(512, 1, 4), 256, 0, stream>>>(W2, W_hi, W_hf, W_ho, wh1, 1024);
  k_conv_w4<<<dim3(512, 1, 4), 256, 0, stream>>>(W1_y, W_xi_y, W_xf_y, W_xo_y, wx2, 1024);
  k_conv_w4<<<dim3(512, 1, 4), 256, 0, stream>>>(W2_y, W_hi_y, W_hf_y, W_ho_y, wh2, 1024);
  k_embed<<<SEQ * BATCH, 256, 0, stream>>>(X, C, xs);
  k_gemx<<<dim3(64, 16), 256, 0, stream>>>(xs, wx1, bc1, G1sw);
  k_mega<<<256, 512, 0, stream>>>(G1sw, wh1, wx2, wh2, bc2, h1ex, h2ex, c0, c0_y, hTy,
                                  flags);
  float* partial = (float*)G1sw;
  k_final<<<dim3(125, 2), 256, 0, stream>>>((const short*)hTy, W3, partial);
  k_fincomb<<<dim3(125, 64), 256, 0, stream>>>(partial, b2, (float*)d_out);
}